// Round 17
// baseline (693.025 us; speedup 1.0000x reference)
//
#include <hip/hip_runtime.h>
#include <stdint.h>

// Round 17: FULL FUSION — gemm1 + attention + gemm2 in one kernel, one block
// (12 waves) per window. qkv never touches HBM (−604MB round-trip, −gemm1
// dispatch). x-tile staged ONCE to LDS (K=384 fits; zero inner barriers ->
// 432 MFMA/wave vs 7 barriers). V accs feed PV A-frags directly (layout
// identity, verified); Q/K take one LDS bounce (qks, stride 776 = spread
// banks) in space reused from the dead x-tile. prep_all frozen (R13).

typedef __attribute__((ext_vector_type(4))) float f32x4;
typedef __attribute__((ext_vector_type(4))) short s16x4;
typedef __attribute__((ext_vector_type(8))) short s16x8;

#define DEVI static __device__ __forceinline__

DEVI unsigned short f2bf(float f) {
  union { float f; uint32_t u; } v; v.f = f;
  return (unsigned short)((v.u + 0x7FFFu + ((v.u >> 16) & 1u)) >> 16);
}

DEVI uint32_t pk2(float lo, float hi) {
  return (uint32_t)f2bf(lo) | ((uint32_t)f2bf(hi) << 16);
}

DEVI f32x4 zero4() { f32x4 z; z[0] = 0.f; z[1] = 0.f; z[2] = 0.f; z[3] = 0.f; return z; }

#if defined(__has_builtin)
#if __has_builtin(__builtin_amdgcn_mfma_f32_16x16x16bf16_1k)
#define MFMA16_BUILTIN 1
#endif
#if __has_builtin(__builtin_amdgcn_global_load_lds)
#define HAS_GLLDS 1
#endif
#endif

DEVI f32x4 mfma16(s16x4 a, s16x4 b, f32x4 c) {
#ifdef MFMA16_BUILTIN
  return __builtin_amdgcn_mfma_f32_16x16x16bf16_1k(a, b, c, 0, 0, 0);
#else
  asm volatile("v_mfma_f32_16x16x16_bf16 %0, %1, %2, %0" : "+v"(c) : "v"(a), "v"(b));
  return c;
#endif
}

DEVI f32x4 mfma32(s16x8 a, s16x8 b, f32x4 c) {
  return __builtin_amdgcn_mfma_f32_16x16x32_bf16(a, b, c, 0, 0, 0);
}

DEVI void stage1k(const unsigned short* g_lane, unsigned short* lds_base) {
#ifdef HAS_GLLDS
  __builtin_amdgcn_global_load_lds(
      (const __attribute__((address_space(1))) unsigned int*)g_lane,
      (__attribute__((address_space(3))) unsigned int*)lds_base, 16, 0, 0);
#else
  *(s16x8*)(lds_base + (threadIdx.x & 63) * 8) = *(const s16x8*)g_lane;
#endif
}

__global__ void fill_val(float* o, int n, float v) {
  int t = blockIdx.x * 256 + threadIdx.x;
  if (t < n) o[t] = v;
}

// ---------------- merged prep (R13 verbatim) ----------------
__global__ __launch_bounds__(256) void prep_all(
    const float* __restrict__ x, unsigned short* __restrict__ xb,
    const float* __restrict__ Wqkv, unsigned short* __restrict__ WqkvT,
    const float* __restrict__ Wm, unsigned short* __restrict__ WmT,
    const float* __restrict__ bqkv, float* __restrict__ bqkvs,
    const float* __restrict__ rel, float* __restrict__ biasF) {
  const int b = blockIdx.x;
  if (b < 2048) {
    const size_t nchunk = 131072UL * 384 / 8;
    for (size_t i = (size_t)b * 256 + threadIdx.x; i < nchunk; i += 2048UL * 256) {
      f32x4 a = *(const f32x4*)(x + i * 8);
      f32x4 c = *(const f32x4*)(x + i * 8 + 4);
      s16x8 p;
      p[0] = (short)f2bf(a[0]); p[1] = (short)f2bf(a[1]);
      p[2] = (short)f2bf(a[2]); p[3] = (short)f2bf(a[3]);
      p[4] = (short)f2bf(c[0]); p[5] = (short)f2bf(c[1]);
      p[6] = (short)f2bf(c[2]); p[7] = (short)f2bf(c[3]);
      *(s16x8*)(xb + i * 8) = p;
    }
  } else if (b == 2048) {
    for (int t = threadIdx.x; t < 1152; t += 256)
      bqkvs[t] = bqkv[t] * ((t < 384) ? 0.17677669529663687f : 1.0f);
  } else if (b < 2097) {
    int t = (b - 2049) * 256 + threadIdx.x;  // 12288
    if (t < 12288) {
      int h = t >> 10;
      int r = (t >> 6) & 15;
      int lane = t & 63;
      int jt = r >> 2, it = r & 3;
      int lg = lane >> 4, lr = lane & 15;
      int i = it * 16 + lr;
#pragma unroll
      for (int e = 0; e < 4; ++e) {
        int j = jt * 16 + lg * 4 + e;
        int idx = ((i >> 3) - (j >> 3) + 7) * 15 + ((i & 7) - (j & 7) + 7);
        biasF[t * 4 + e] = rel[idx * 12 + h];
      }
    }
  } else if (b < 2673) {
    int t = (b - 2097) * 256 + threadIdx.x;  // 147456
    int n = t / 384, k = t - n * 384;
    WmT[t] = f2bf(Wm[(size_t)k * 384 + n]);
  } else {
    int t = (b - 2673) * 256 + threadIdx.x;  // 442368
    int n = t / 384, k = t - n * 384;
    float s = (n < 384) ? 0.17677669529663687f : 1.0f;
    WqkvT[t] = f2bf(Wqkv[(size_t)k * 1152 + n] * s);
  }
}

// ---------------- fully fused: gemm1 + attention + gemm2, one block/window -------
// LDS unions (99328 B total):
//   x_s  [64][512] shorts (65536 B)  — x tile, swizzled chunks; dies after pass-QK
//   qks  [64][776] shorts (99328 B)  — Q|K cols 0..767; dies after frag read
//   att_s[64][392] shorts (50176 B)  — attn output for phase-2
__global__ __launch_bounds__(768) void fused_k(const unsigned short* __restrict__ xb,
                                               const unsigned short* __restrict__ WqkvT,
                                               const float* __restrict__ bqkvs,
                                               const float* __restrict__ biasF,
                                               const unsigned short* __restrict__ WmT,
                                               const float* __restrict__ bm,
                                               float* __restrict__ out) {
  __shared__ __attribute__((aligned(16))) unsigned short smem[49664];
  unsigned short* x_s = smem;
  unsigned short* qks = smem;
  unsigned short* att_s = smem;

  const int lane = threadIdx.x & 63;
  const int wv = threadIdx.x >> 6;  // 0..11; attn phase: head wv
  const int window = blockIdx.x;    // [0, 2048)
  const int lg = lane >> 4, lr = lane & 15;

  // ---- stage x tile: row r = one 1KB wave-call; LDS chunk l <- global chunk l^(r&7)
  for (int r = wv; r < 64; r += 12) {
    const unsigned short* src =
        xb + (size_t)(window * 64 + r) * 384 + (size_t)((lane ^ (r & 7)) * 8);
    stage1k(src, &x_s[r * 512]);
  }
  __syncthreads();  // drains vmcnt (order-independent)

  // A-frag read helper: global chunk c of row -> LDS chunk c^(lr&7)  (row&7 == lr&7)
  // addr shorts = row*512 + ((ks*4+lg) ^ (lr&7))*8
#define AF(mt, ks) \
  (*(const s16x8*)&x_s[(16 * (mt) + lr) * 512 + (((ks) * 4 + lg) ^ (lr & 7)) * 8])

  // ---- pass V: wave wv -> head wv's V cols (WqkvT rows 768+wv*32 .. +32)
  f32x4 accv[4][2];
#pragma unroll
  for (int mt = 0; mt < 4; ++mt)
#pragma unroll
    for (int nt = 0; nt < 2; ++nt) accv[mt][nt] = zero4();
  {
    const unsigned short* W0 = WqkvT + (size_t)(768 + wv * 32 + lr) * 384 + 8 * lg;
    const unsigned short* W1 = W0 + (size_t)16 * 384;
#pragma unroll
    for (int ks = 0; ks < 12; ++ks) {
      s16x8 bf0 = *(const s16x8*)(W0 + ks * 32);
      s16x8 bf1 = *(const s16x8*)(W1 + ks * 32);
#pragma unroll
      for (int mt = 0; mt < 4; ++mt) {
        s16x8 a = AF(mt, ks);
        accv[mt][0] = mfma32(a, bf0, accv[mt][0]);
        accv[mt][1] = mfma32(a, bf1, accv[mt][1]);
      }
    }
  }
  // bias + pack: va[jt][dt] = V[token=16jt+4lg+e][d=16dt+lr]  (direct PV A-frag)
  s16x4 va[4][2];
#pragma unroll
  for (int dt = 0; dt < 2; ++dt) {
    const float bv = bqkvs[768 + wv * 32 + dt * 16 + lr];
#pragma unroll
    for (int jt = 0; jt < 4; ++jt) {
      s16x4 pk;
#pragma unroll
      for (int e = 0; e < 4; ++e) pk[e] = (short)f2bf(accv[jt][dt][e] + bv);
      va[jt][dt] = pk;
    }
  }

  // ---- pass QK: wave wv -> qkcols [wv*64, wv*64+64)  (WqkvT rows 0..767)
  f32x4 acck[4][4];
#pragma unroll
  for (int mt = 0; mt < 4; ++mt)
#pragma unroll
    for (int nt = 0; nt < 4; ++nt) acck[mt][nt] = zero4();
  {
    const unsigned short* Wq = WqkvT + (size_t)(wv * 64 + lr) * 384 + 8 * lg;
#pragma unroll
    for (int ks = 0; ks < 12; ++ks) {
      s16x8 bf[4];
#pragma unroll
      for (int nt = 0; nt < 4; ++nt)
        bf[nt] = *(const s16x8*)(Wq + (size_t)(16 * nt) * 384 + ks * 32);
#pragma unroll
      for (int mt = 0; mt < 4; ++mt) {
        s16x8 a = AF(mt, ks);
#pragma unroll
        for (int nt = 0; nt < 4; ++nt) acck[mt][nt] = mfma32(a, bf[nt], acck[mt][nt]);
      }
    }
  }
  __syncthreads();  // x_s dead; qks space safe to write

  // ---- bounce Q,K -> qks[token][qkcol], stride 776 (word stride ≡ 4 mod 32)
#pragma unroll
  for (int nt = 0; nt < 4; ++nt) {
    const int qkcol = wv * 64 + 16 * nt + lr;
    const float bv = bqkvs[qkcol];
#pragma unroll
    for (int mt = 0; mt < 4; ++mt)
#pragma unroll
      for (int e = 0; e < 4; ++e)
        qks[(16 * mt + 4 * lg + e) * 776 + qkcol] = f2bf(acck[mt][nt][e] + bv);
  }
  __syncthreads();  // qks ready

  // ---- attn frags for head wv
  s16x8 ka[4], qb[4];
#pragma unroll
  for (int jt = 0; jt < 4; ++jt)
    ka[jt] = *(const s16x8*)&qks[(16 * jt + lr) * 776 + 384 + wv * 32 + 8 * lg];
#pragma unroll
  for (int it = 0; it < 4; ++it)
    qb[it] = *(const s16x8*)&qks[(16 * it + lr) * 776 + wv * 32 + 8 * lg];
  __syncthreads();  // all frags read; qks dead (att_s overlaps)

  // ---- attention (R15 verbatim math)
  f32x4 c[4][4];
#pragma unroll
  for (int a = 0; a < 4; ++a)
#pragma unroll
    for (int b2 = 0; b2 < 4; ++b2) c[a][b2] = zero4();

#pragma unroll
  for (int jt = 0; jt < 4; ++jt)
#pragma unroll
    for (int it = 0; it < 4; ++it)
      c[jt][it] = mfma32(ka[jt], qb[it], c[jt][it]);

  const f32x4* bF = (const f32x4*)biasF + ((size_t)wv * 16) * 64 + lane;
#pragma unroll
  for (int jt = 0; jt < 4; ++jt)
#pragma unroll
    for (int it = 0; it < 4; ++it)
      c[jt][it] += bF[(jt * 4 + it) * 64];

  s16x4 pb[4][4];
#pragma unroll
  for (int it = 0; it < 4; ++it) {
    float m = -3.0e38f;
#pragma unroll
    for (int jt = 0; jt < 4; ++jt)
#pragma unroll
      for (int e = 0; e < 4; ++e) m = fmaxf(m, c[jt][it][e]);
    m = fmaxf(m, __shfl_xor(m, 16));
    m = fmaxf(m, __shfl_xor(m, 32));
    float s = 0.f;
#pragma unroll
    for (int jt = 0; jt < 4; ++jt)
#pragma unroll
      for (int e = 0; e < 4; ++e) {
        float p = __expf(c[jt][it][e] - m);
        c[jt][it][e] = p;
        s += p;
      }
    s += __shfl_xor(s, 16);
    s += __shfl_xor(s, 32);
    const float inv = 1.f / s;
#pragma unroll
    for (int jt = 0; jt < 4; ++jt) {
      s16x4 pk;
#pragma unroll
      for (int e = 0; e < 4; ++e) pk[e] = (short)f2bf(c[jt][it][e] * inv);
      pb[jt][it] = pk;
    }
  }

  f32x4 o[2][4];
#pragma unroll
  for (int a = 0; a < 2; ++a)
#pragma unroll
    for (int b2 = 0; b2 < 4; ++b2) o[a][b2] = zero4();

#pragma unroll
  for (int jt = 0; jt < 4; ++jt)
#pragma unroll
    for (int dt = 0; dt < 2; ++dt)
#pragma unroll
      for (int it = 0; it < 4; ++it)
        o[dt][it] = mfma16(va[jt][dt], pb[jt][it], o[dt][it]);

  // ---- R14 4-lane transpose -> att_s
#pragma unroll
  for (int it = 0; it < 4; ++it) {
    const uint32_t p0 = pk2(o[0][it][0], o[0][it][1]);
    const uint32_t p1 = pk2(o[0][it][2], o[0][it][3]);
    const uint32_t q0 = pk2(o[1][it][0], o[1][it][1]);
    const uint32_t q1 = pk2(o[1][it][2], o[1][it][3]);

    const uint32_t x16_0 = __shfl_xor((int)(lg == 2 ? q0 : p0), 16);
    const uint32_t x16_1 = __shfl_xor((int)(lg == 2 ? q1 : p1), 16);
    const uint32_t x32_0 = __shfl_xor((int)(lg == 0 ? q0 : p0), 32);
    const uint32_t x32_1 = __shfl_xor((int)(lg == 0 ? q1 : p1), 32);
    const uint32_t x48_0 = __shfl_xor((int)(lg == 1 ? q0 : p0), 48);
    const uint32_t x48_1 = __shfl_xor((int)(lg == 1 ? q1 : p1), 48);

    uint32_t w[4];
    w[0] = lg == 0 ? p0 : lg == 1 ? x48_0 : lg == 2 ? x32_0 : x16_0;
    w[1] = lg == 0 ? p1 : lg == 1 ? x48_1 : lg == 2 ? x32_1 : x16_1;
    w[2] = lg == 0 ? x16_0 : lg == 1 ? x32_0 : lg == 2 ? x48_0 : q0;
    w[3] = lg == 0 ? x16_1 : lg == 1 ? x32_1 : lg == 2 ? x48_1 : q1;

    *(uint4*)&att_s[(size_t)(it * 16 + lr) * 392 + wv * 32 + 8 * lg] =
        make_uint4(w[0], w[1], w[2], w[3]);
  }

  __syncthreads();

  // ---- phase 2: GEMM2 (R15 verbatim). wave wv -> cols [wv*32, +32)
  f32x4 acc[4][2];
#pragma unroll
  for (int mt = 0; mt < 4; ++mt)
#pragma unroll
    for (int nt = 0; nt < 2; ++nt) acc[mt][nt] = zero4();

  const int n0w = wv * 32;
#pragma unroll 2
  for (int ks = 0; ks < 12; ++ks) {
    s16x8 af[4], bf[2];
#pragma unroll
    for (int mt = 0; mt < 4; ++mt)
      af[mt] = *(const s16x8*)&att_s[(16 * mt + lr) * 392 + ks * 32 + 8 * lg];
#pragma unroll
    for (int nt = 0; nt < 2; ++nt)
      bf[nt] = *(const s16x8*)&WmT[(size_t)(n0w + 16 * nt + lr) * 384 + ks * 32 + 8 * lg];
#pragma unroll
    for (int mt = 0; mt < 4; ++mt)
#pragma unroll
      for (int nt = 0; nt < 2; ++nt)
        acc[mt][nt] = mfma32(af[mt], bf[nt], acc[mt][nt]);
  }

  float* ob = out + (size_t)window * 64 * 384;
#pragma unroll
  for (int mt = 0; mt < 4; ++mt)
#pragma unroll
    for (int nt = 0; nt < 2; ++nt) {
      const int col = n0w + 16 * nt + lr;
      const float bv = bm[col];
#pragma unroll
      for (int e = 0; e < 4; ++e)
        ob[(size_t)(16 * mt + 4 * lg + e) * 384 + col] = acc[mt][nt][e] + bv;
    }
#undef AF
}

extern "C" void kernel_launch(void* const* d_in, const int* in_sizes, int n_in,
                              void* d_out, int out_size, void* d_ws, size_t ws_size,
                              hipStream_t stream) {
  const float* x = (const float*)d_in[0];
  const float* Wqkv = (const float*)d_in[1];
  const float* bqkv = (const float*)d_in[2];
  const float* Wm = (const float*)d_in[3];
  const float* bm = (const float*)d_in[4];
  const float* rel = (const float*)d_in[5];

  const size_t M = 131072;  // B*G*P
  char* ws = (char*)d_ws;
  size_t off = 0;
  unsigned short* xb = (unsigned short*)(ws + off);    off += M * 384 * 2;  // 100 MB
  unsigned short* WqkvT = (unsigned short*)(ws + off); off += 1152 * 384 * 2;
  unsigned short* WmT = (unsigned short*)(ws + off);   off += 384 * 384 * 2;
  float* biasF = (float*)(ws + off);                   off += 12 * 16 * 64 * 4 * 4;
  float* bqkvs = (float*)(ws + off);                   off += 1152 * 4;
  off += 1024;  // slack for the staging over-read at xb end (reads into WqkvT region)

  if (ws_size < off) {
    fill_val<<<(out_size + 255) / 256, 256, 0, stream>>>((float*)d_out, out_size, 12345.0f);
    return;
  }

  prep_all<<<4401, 256, 0, stream>>>(x, xb, Wqkv, WqkvT, Wm, WmT, bqkv, bqkvs, rel, biasF);
  fused_k<<<2048, 768, 0, stream>>>(xb, WqkvT, bqkvs, biasF, WmT, bm, (float*)d_out);
}